// Round 1
// baseline (1035.912 us; speedup 1.0000x reference)
//
#include <hip/hip_runtime.h>

// Problem constants (fixed shapes from reference)
#define NE    1024
#define CDIM  64
#define BDIM  16
#define HDIM  64
#define WDIM  64
#define NPOS  (BDIM*HDIM*WDIM)          // 65536 positions
#define ZTOT  (BDIM*CDIM*HDIM*WDIM)     // 4194304 elements

// d_out offsets (float elements), concat in reference return order
#define ZQ_OFF   0
#define LOSS_OFF 4194304
#define IDX_OFF  4194305
#define EMB_OFF  4259841
#define CS_OFF   4325377
#define EA_OFF   4326401

// workspace offsets (float elements)
#define WS_LOSS   0
#define WS_COUNTS 64
#define WS_ESUM   (64 + 1024)
#define WS_ENORM  (64 + 1024 + 65536)
#define WS_CSN    (WS_ENORM + 1024)
#define WS_ZERO_BYTES ((size_t)(64 + 1024 + 65536) * 4)

// ---------------- K0: codebook row squared norms ----------------
__global__ __launch_bounds__(256) void k_enorm(const float* __restrict__ emb,
                                               float* __restrict__ enorm) {
    int wid  = (blockIdx.x * blockDim.x + threadIdx.x) >> 6;   // row 0..1023
    int lane = threadIdx.x & 63;
    if (wid >= NE) return;
    float v = emb[wid * CDIM + lane];
    float s = v * v;
    #pragma unroll
    for (int off = 32; off > 0; off >>= 1) s += __shfl_xor(s, off);
    if (lane == 0) enorm[wid] = s;
}

// ---------------- K1: argmin + z_q + loss + scatter ----------------
__global__ __launch_bounds__(256) void k_main(const float* __restrict__ z,
                                              const float* __restrict__ emb,
                                              const float* __restrict__ enorm,
                                              float* __restrict__ out,
                                              float* __restrict__ counts,
                                              float* __restrict__ esum,
                                              float* __restrict__ lossacc) {
    const int lane = threadIdx.x & 63;                // w
    const int bh   = blockIdx.x * 4 + (threadIdx.x >> 6);  // 0..1023
    const int b    = bh >> 6;
    const int h    = bh & 63;
    const int zbase = b * (CDIM * HDIM * WDIM) + h * WDIM + lane;

    // load this position's 64-dim vector (coalesced across lanes)
    float zr[CDIM];
    #pragma unroll
    for (int c = 0; c < CDIM; ++c) zr[c] = z[zbase + c * (HDIM * WDIM)];

    // argmin over codebook: maximize dot - 0.5*||e||^2  (== argmin distance)
    float best = -3.4e38f;
    int bidx = 0;
    for (int j = 0; j < NE; ++j) {
        const float* e = emb + j * CDIM;   // wave-uniform address -> s_load
        float d0 = 0.f, d1 = 0.f, d2 = 0.f, d3 = 0.f;
        #pragma unroll
        for (int c = 0; c < CDIM; c += 4) {
            d0 = fmaf(e[c + 0], zr[c + 0], d0);
            d1 = fmaf(e[c + 1], zr[c + 1], d1);
            d2 = fmaf(e[c + 2], zr[c + 2], d2);
            d3 = fmaf(e[c + 3], zr[c + 3], d3);
        }
        float dot = (d0 + d1) + (d2 + d3);
        float m = fmaf(-0.5f, enorm[j], dot);
        if (m > best) { best = m; bidx = j; }   // strict > keeps first index on ties
    }

    // indices output (stored as float; harness reads whole buffer as f32)
    out[IDX_OFF + bh * 64 + lane] = (float)bidx;

    // fetch selected codebook row (per-lane divergent gather, float4)
    const float4* ev = (const float4*)(emb + bidx * CDIM);
    float lsum = 0.f;

    #define PROC(ZQ, CC)                                                    \
        do {                                                                \
            const int c_ = (CC);                                            \
            float zv_ = zr[c_];                                             \
            float df_ = (ZQ) - zv_;                                         \
            out[ZQ_OFF + zbase + c_ * (HDIM * WDIM)] = zv_ + df_;           \
            lsum = fmaf(df_, df_, lsum);                                    \
            atomicAdd(&esum[bidx * CDIM + c_], zv_);                        \
        } while (0)

    #pragma unroll
    for (int k = 0; k < 16; ++k) {
        float4 e4 = ev[k];
        PROC(e4.x, 4 * k + 0);
        PROC(e4.y, 4 * k + 1);
        PROC(e4.z, 4 * k + 2);
        PROC(e4.w, 4 * k + 3);
    }
    #undef PROC

    atomicAdd(&counts[bidx], 1.0f);

    // wave-reduce commitment-loss partial, one atomic per wave
    #pragma unroll
    for (int off = 32; off > 0; off >>= 1) lsum += __shfl_xor(lsum, off);
    if (lane == 0) atomicAdd(lossacc, lsum);
}

// ---------------- K2: cluster-size EMA + n-sum + loss ----------------
__global__ __launch_bounds__(1024) void k_cluster(const float* __restrict__ cs_in,
                                                  const float* __restrict__ counts,
                                                  const float* __restrict__ lossacc,
                                                  float* __restrict__ out,
                                                  float* __restrict__ csn) {
    __shared__ float red[NE];
    int j = threadIdx.x;
    float ncs = 0.99f * cs_in[j] + 0.01f * counts[j];
    out[CS_OFF + j] = ncs;
    red[j] = ncs;
    __syncthreads();
    #pragma unroll
    for (int s = 512; s > 0; s >>= 1) {
        if (j < s) red[j] += red[j + s];
        __syncthreads();
    }
    float n = red[0];
    float cs = ((ncs + 1e-5f) / (n + 0.01024f)) * n;   // (ncs+eps)/(n+NE*eps)*n
    csn[j] = cs;
    if (j == 0) out[LOSS_OFF] = 0.25f * (lossacc[0] * (1.0f / (float)ZTOT));
}

// ---------------- K3: embed_avg EMA + normalized embedding ----------------
__global__ __launch_bounds__(256) void k_embed(const float* __restrict__ ea_in,
                                               const float* __restrict__ esum,
                                               const float* __restrict__ csn,
                                               float* __restrict__ out) {
    int i = blockIdx.x * 256 + threadIdx.x;   // 0..65535
    float nea = 0.99f * ea_in[i] + 0.01f * esum[i];
    out[EA_OFF + i] = nea;
    out[EMB_OFF + i] = nea / csn[i >> 6];
}

extern "C" void kernel_launch(void* const* d_in, const int* in_sizes, int n_in,
                              void* d_out, int out_size, void* d_ws, size_t ws_size,
                              hipStream_t stream) {
    const float* z   = (const float*)d_in[0];
    const float* emb = (const float*)d_in[1];
    const float* cs  = (const float*)d_in[2];
    const float* ea  = (const float*)d_in[3];
    float* out = (float*)d_out;
    float* ws  = (float*)d_ws;

    hipMemsetAsync(d_ws, 0, WS_ZERO_BYTES, stream);                 // loss + counts + esum
    k_enorm<<<256, 256, 0, stream>>>(emb, ws + WS_ENORM);
    k_main<<<256, 256, 0, stream>>>(z, emb, ws + WS_ENORM, out,
                                    ws + WS_COUNTS, ws + WS_ESUM, ws + WS_LOSS);
    k_cluster<<<1, 1024, 0, stream>>>(cs, ws + WS_COUNTS, ws + WS_LOSS, out, ws + WS_CSN);
    k_embed<<<256, 256, 0, stream>>>(ea, ws + WS_ESUM, ws + WS_CSN, out);
}